// Round 2
// baseline (450.744 us; speedup 1.0000x reference)
//
#include <hip/hip_runtime.h>
#include <hip/hip_bf16.h>
#include <stdint.h>

#define NROWS   131072
#define LMD     1024
#define GNND    200
#define K2      256              // gnn K padded to 256 (W zero-padded)
#define HD      128
#define BLOCK   256
#define MTILE   64               // rows per block (16 per wave)
#define NBLK    (NROWS/MTILE)    // 2048
#define KC      64               // k-chunk elements
#define CHB     (MTILE*KC*4)     // chunk bytes = 16384

typedef __attribute__((ext_vector_type(4))) float  f32x4;
typedef __attribute__((ext_vector_type(8))) short  bf16x8;

__device__ __forceinline__ short f2bf(float x) {
    union { __hip_bfloat16 h; short s; } u;
    u.h = __float2bfloat16(x);
    return u.s;
}

__device__ __forceinline__ bf16x8 cvt8(f32x4 a, f32x4 b) {
    bf16x8 r;
    r[0]=f2bf(a[0]); r[1]=f2bf(a[1]); r[2]=f2bf(a[2]); r[3]=f2bf(a[3]);
    r[4]=f2bf(b[0]); r[5]=f2bf(b[1]); r[6]=f2bf(b[2]); r[7]=f2bf(b[3]);
    return r;
}

__device__ __forceinline__ float red16(float v) {
    #pragma unroll
    for (int m=1; m<16; m<<=1) v += __shfl_xor(v, m, 16);
    return v;
}

// ---- prep: W1B[h][k]=bf16(lm_W[k][h]) [128][1024]; W2B[h][k]=bf16(gnn_W[k][h]) [128][256] zero-padded ----
__global__ void prep_weights(const float* __restrict__ lm_W,
                             const float* __restrict__ gnn_W,
                             short* __restrict__ W1B, short* __restrict__ W2B)
{
    int idx = blockIdx.x*BLOCK + threadIdx.x;        // grid = 512*256 = 131072 = HD*LMD
    { int h = idx >> 10, k = idx & 1023; W1B[idx] = f2bf(lm_W[(long)k*HD + h]); }
    if (idx < HD*K2) {
        int h = idx >> 8, k = idx & 255;
        W2B[idx] = f2bf(k < GNND ? gnn_W[(long)k*HD + h] : 0.0f);
    }
}

// Stage one [64 rows][64 k] f32 tile (16KB) into LDS, linear dest, pre-swizzled source.
// Physical layout: rows of 256B; phys(row,c') holds logical c = c' ^ ((row&7)<<4).
__device__ __forceinline__ void stage_tile(const char* __restrict__ Abase, long rowBytes, int k0,
                                           char* buf, int tid, const char* clampP)
{
    const int rsub = tid >> 4;                  // 0..15 (sub-row within 16-row stripe)
    const int sw   = (rsub & 7) << 4;
    const int c    = ((tid & 15) * 16) ^ sw;    // logical col byte (multiple of 16, <256)
    #pragma unroll
    for (int i = 0; i < 4; ++i) {
        const char* src = Abase + (long)(i*16 + rsub) * rowBytes + (long)k0*4 + c;
        if (clampP && src > clampP) src = clampP;
        __builtin_amdgcn_global_load_lds(
            (const __attribute__((address_space(1))) unsigned int*)src,
            (__attribute__((address_space(3))) unsigned int*)(buf + i*4096 + tid*16),
            16, 0, 0);
    }
}

// One GEMM phase: acc[t] (+= over K) for this wave's 16 rows x 128 cols.
template<int NCH, int WK>
__device__ __forceinline__ void gemm_phase(const char* __restrict__ Arow0, long rowBytes,
                                           const short* __restrict__ WT,
                                           const char* clampP, char* lds0, char* lds1,
                                           int tid, int col, int g, int win, f32x4 (&acc)[8])
{
    const f32x4 fz = {0.f,0.f,0.f,0.f};
    #pragma unroll
    for (int t=0;t<8;t++) acc[t] = fz;

    stage_tile(Arow0, rowBytes, 0, lds0, tid, clampP);
    __syncthreads();

    const int arow = win*16 + col;
    const int sw   = (col & 7) << 4;
    char* cur = lds0;
    char* nxt = lds1;
    for (int ch = 0; ch < NCH; ++ch) {
        if (ch+1 < NCH) stage_tile(Arow0, rowBytes, (ch+1)*KC, nxt, tid, clampP);
        #pragma unroll
        for (int ks = 0; ks < 2; ++ks) {
            const int cbyte = (ks*32 + g*8)*4;
            f32x4 a0 = *(const f32x4*)(cur + arow*256 + (cbyte ^ sw));
            f32x4 a1 = *(const f32x4*)(cur + arow*256 + ((cbyte+16) ^ sw));
            bf16x8 af = cvt8(a0, a1);
            const int kk = ch*KC + ks*32 + g*8;
            #pragma unroll
            for (int t=0;t<8;t++) {
                bf16x8 bf = *(const bf16x8*)(WT + (long)(t*16+col)*WK + kk);
                acc[t] = __builtin_amdgcn_mfma_f32_16x16x32_bf16(af, bf, acc[t], 0,0,0);
            }
        }
        __syncthreads();                 // drains next-stage vmcnt + read-done for cur
        char* tmp = cur; cur = nxt; nxt = tmp;
    }
}

__global__ __launch_bounds__(BLOCK, 3) void fused(
    const float* __restrict__ lm,  const float* __restrict__ gnn,
    const float* __restrict__ ngn,
    const float* __restrict__ lm_b, const float* __restrict__ gnn_b,
    const short* __restrict__ W1B,  const short* __restrict__ W2B,
    float* __restrict__ partials)
{
    __shared__ char lds[2*CHB];
    char* lds0 = lds;
    char* lds1 = lds + CHB;

    const int tid  = threadIdx.x;
    const int lane = tid & 63;
    const int win  = tid >> 6;
    const int col  = lane & 15;
    const int g    = lane >> 4;
    const long r0  = (long)blockIdx.x * MTILE;

    const float CC   = 1.0f / 11008.0f;
    const float LOGC = -9.3063777f;      // log(1/11008)

    f32x4 accL[8], accG[8];
    float pos_acc = 0.f, neg_acc = 0.f;

    // ---- lm GEMM ----
    gemm_phase<LMD/KC, LMD>((const char*)(lm + r0*LMD), (long)LMD*4, W1B, nullptr,
                            lds0, lds1, tid, col, g, win, accL);
    #pragma unroll
    for (int t=0;t<8;t++) {
        float b = lm_b[t*16+col];
        #pragma unroll
        for (int r=0;r<4;r++) accL[t][r] += b;
    }

    const char* clampG = (const char*)gnn + (size_t)NROWS*GNND*4 - 16;
    const char* clampN = (const char*)ngn + (size_t)NROWS*GNND*4 - 16;

    // ---- pos branch ----
    gemm_phase<K2/KC, K2>((const char*)gnn + r0*(long)GNND*4, (long)GNND*4, W2B, clampG,
                          lds0, lds1, tid, col, g, win, accG);
    #pragma unroll
    for (int t=0;t<8;t++) {
        float b = gnn_b[t*16+col];
        #pragma unroll
        for (int r=0;r<4;r++) accG[t][r] += b;
    }
    #pragma unroll
    for (int r=0;r<4;r++) {
        float lg=0.f, ll=0.f, gg=0.f;
        #pragma unroll
        for (int t=0;t<8;t++) {
            float lv=accL[t][r], gv=accG[t][r];
            lg += lv*gv; ll += lv*lv; gg += gv*gv;
        }
        lg=red16(lg); ll=red16(ll); gg=red16(gg);
        float d  = lg * rsqrtf(ll*gg);
        float pi = d - logf(expf(d)+CC);     // log(ratio)
        if (col==0) pos_acc += pi;
    }

    // ---- neg branch ----
    gemm_phase<K2/KC, K2>((const char*)ngn + r0*(long)GNND*4, (long)GNND*4, W2B, clampN,
                          lds0, lds1, tid, col, g, win, accG);
    #pragma unroll
    for (int t=0;t<8;t++) {
        float b = gnn_b[t*16+col];
        #pragma unroll
        for (int r=0;r<4;r++) accG[t][r] += b;
    }
    #pragma unroll
    for (int r=0;r<4;r++) {
        float ln=0.f, nn=0.f, ll=0.f;
        #pragma unroll
        for (int t=0;t<8;t++) {
            float lv=accL[t][r], nv=accG[t][r];
            ln += lv*nv; nn += nv*nv; ll += lv*lv;
        }
        ln=red16(ln); nn=red16(nn); ll=red16(ll);
        float d  = ln * rsqrtf(ll*nn);
        float ni = LOGC - logf(expf(d)+CC);  // log(1-ratio)
        if (col==0) neg_acc += ni;
    }

    // ---- wave + block reduce ----
    #pragma unroll
    for (int m=1;m<64;m<<=1) {
        pos_acc += __shfl_xor(pos_acc, m, 64);
        neg_acc += __shfl_xor(neg_acc, m, 64);
    }
    __shared__ float sp[4], sn[4];
    if (lane==0) { sp[win]=pos_acc; sn[win]=neg_acc; }
    __syncthreads();
    if (tid==0) {
        float p=0.f,n=0.f;
        #pragma unroll
        for (int w=0;w<4;w++){ p+=sp[w]; n+=sn[w]; }
        partials[blockIdx.x*2]   = p;
        partials[blockIdx.x*2+1] = n;
    }
}

__global__ void finalize(const float* __restrict__ partials, float* __restrict__ out)
{
    __shared__ float sp[BLOCK], sn[BLOCK];
    float p=0.f, n=0.f;
    for (int i=threadIdx.x; i<NBLK; i+=BLOCK) { p += partials[2*i]; n += partials[2*i+1]; }
    sp[threadIdx.x]=p; sn[threadIdx.x]=n;
    __syncthreads();
    for (int s=BLOCK/2; s>0; s>>=1) {
        if (threadIdx.x < s) { sp[threadIdx.x]+=sp[threadIdx.x+s]; sn[threadIdx.x]+=sn[threadIdx.x+s]; }
        __syncthreads();
    }
    if (threadIdx.x==0) out[0] = -(sp[0]+sn[0]) / (float)NROWS;
}

extern "C" void kernel_launch(void* const* d_in, const int* in_sizes, int n_in,
                              void* d_out, int out_size, void* d_ws, size_t ws_size,
                              hipStream_t stream)
{
    const float* lm    = (const float*)d_in[0];
    const float* gnn   = (const float*)d_in[1];
    const float* ngn   = (const float*)d_in[2];
    const float* lm_W  = (const float*)d_in[3];
    const float* lm_b  = (const float*)d_in[4];
    const float* gnn_W = (const float*)d_in[5];
    const float* gnn_b = (const float*)d_in[6];

    short* W1B = (short*)d_ws;                                   // 128*1024*2 = 262144 B
    short* W2B = (short*)((char*)d_ws + 262144);                 // 128*256*2  =  65536 B
    float* partials = (float*)((char*)d_ws + 262144 + 65536);    // 16 KB

    prep_weights<<<512, BLOCK, 0, stream>>>(lm_W, gnn_W, W1B, W2B);
    fused<<<NBLK, BLOCK, 0, stream>>>(lm, gnn, ngn, lm_b, gnn_b, W1B, W2B, partials);
    finalize<<<1, BLOCK, 0, stream>>>(partials, (float*)d_out);
}

// Round 3
// 210.917 us; speedup vs baseline: 2.1371x; 2.1371x over previous
//
#include <hip/hip_runtime.h>
#include <hip/hip_bf16.h>
#include <stdint.h>

#define NROWS   131072
#define LMD     1024
#define GNND    200
#define K2      256              // gnn K padded to 256 (W zero-padded)
#define HD      128
#define BLOCK   256
#define MTILE   128              // rows per block (32 per wave)
#define NBLK    (NROWS/MTILE)    // 1024
#define PS      72               // LDS row stride in shorts (144 B, conflict-free)
#define LBUF    (128*PS)         // one W chunk buffer (shorts)

typedef __attribute__((ext_vector_type(4))) float  f32x4;
typedef __attribute__((ext_vector_type(8))) short  bf16x8;

__device__ __forceinline__ short f2bf(float x) {
    union { __hip_bfloat16 h; short s; } u;
    u.h = __float2bfloat16(x);
    return u.s;
}

__device__ __forceinline__ bf16x8 cvt8(f32x4 a, f32x4 b) {
    bf16x8 r;
    r[0]=f2bf(a[0]); r[1]=f2bf(a[1]); r[2]=f2bf(a[2]); r[3]=f2bf(a[3]);
    r[4]=f2bf(b[0]); r[5]=f2bf(b[1]); r[6]=f2bf(b[2]); r[7]=f2bf(b[3]);
    return r;
}

__device__ __forceinline__ float red16(float v) {
    #pragma unroll
    for (int m=1; m<16; m<<=1) v += __shfl_xor(v, m, 16);
    return v;
}

// ---- prep: W1B[h][k]=bf16(lm_W[k][h]) [128][1024]; W2B[h][k]=bf16(gnn_W[k][h]) [128][256] zero-padded ----
__global__ void prep_weights(const float* __restrict__ lm_W,
                             const float* __restrict__ gnn_W,
                             short* __restrict__ W1B, short* __restrict__ W2B)
{
    int idx = blockIdx.x*BLOCK + threadIdx.x;        // 512*256 = 131072 = HD*LMD
    { int h = idx >> 10, k = idx & 1023; W1B[idx] = f2bf(lm_W[(long)k*HD + h]); }
    if (idx < HD*K2) {
        int h = idx >> 8, k = idx & 255;
        W2B[idx] = f2bf(k < GNND ? gnn_W[(long)k*HD + h] : 0.0f);
    }
}

// One GEMM phase over K = NCH*64 for this wave's 32 rows x 128 cols.
// A: global->reg, depth-2 kstep prefetch. W: global->reg->LDS, double-buffered,
// one barrier per 64-k chunk, staged loads overlap compute.
template<int NCH, int WK, bool CLAMP>
__device__ __forceinline__ void gemm_phase(const char* Abase, long rowB,
                                           const short* __restrict__ Wsrc,
                                           const char* clampP, short* lds,
                                           int tid, int col, int g,
                                           f32x4 (&acc)[2][8])
{
    const f32x4 fz = {0.f,0.f,0.f,0.f};
    #pragma unroll
    for (int m=0;m<2;m++)
        #pragma unroll
        for (int t=0;t<8;t++) acc[m][t] = fz;

    // staging map: unit u = i*256+tid -> row = i*32 + (tid>>3), 16B-seg q = tid&7
    const int srow = tid >> 3;
    const int sq   = tid & 7;
    const short* ws = Wsrc + (long)srow*WK + sq*8;
    short*       ld = lds  + srow*PS + sq*8;

    const char* a0 = Abase + (long)col*rowB      + g*32;
    const char* a1 = Abase + (long)(16+col)*rowB + g*32;

    auto LOADA = [&](int J, f32x4& sa, f32x4& sb, f32x4& sc, f32x4& sd) {
        const char* p0 = a0 + (long)J*128;
        const char* p1 = p0 + 16;
        const char* q0 = a1 + (long)J*128;
        const char* q1 = q0 + 16;
        if constexpr (CLAMP) {
            if (p0 > clampP) p0 = clampP;
            if (p1 > clampP) p1 = clampP;
            if (q0 > clampP) q0 = clampP;
            if (q1 > clampP) q1 = clampP;
        }
        sa = *(const f32x4*)p0; sb = *(const f32x4*)p1;
        sc = *(const f32x4*)q0; sd = *(const f32x4*)q1;
    };

    bf16x8 w0,w1,w2,w3;
    f32x4 s0a,s0b,s0c,s0d, s1a,s1b,s1c,s1d;

    // prologue: issue W(0), then A(0),A(1); write W(0) to buf0
    w0 = *(const bf16x8*)(ws + 0*32*WK);
    w1 = *(const bf16x8*)(ws + 1*32*WK);
    w2 = *(const bf16x8*)(ws + 2*32*WK);
    w3 = *(const bf16x8*)(ws + 3*32*WK);
    LOADA(0, s0a,s0b,s0c,s0d);
    LOADA(1, s1a,s1b,s1c,s1d);
    *(bf16x8*)(ld + 0*32*PS) = w0;
    *(bf16x8*)(ld + 1*32*PS) = w1;
    *(bf16x8*)(ld + 2*32*PS) = w2;
    *(bf16x8*)(ld + 3*32*PS) = w3;
    __syncthreads();

    for (int ch = 0; ch < NCH; ++ch) {
        const short* cur  = lds + (ch&1)*LBUF;
        short*       nxtd = ld  + ((ch+1)&1)*LBUF;
        const bool more = (ch+1 < NCH);
        if (more) {
            const short* wsc = ws + (ch+1)*64;
            w0 = *(const bf16x8*)(wsc + 0*32*WK);
            w1 = *(const bf16x8*)(wsc + 1*32*WK);
            w2 = *(const bf16x8*)(wsc + 2*32*WK);
            w3 = *(const bf16x8*)(wsc + 3*32*WK);
        }
        // ks = 0  (kstep j = 2ch)
        {
            bf16x8 af0 = cvt8(s0a,s0b);
            bf16x8 af1 = cvt8(s0c,s0d);
            if (more) LOADA(2*ch+2, s0a,s0b,s0c,s0d);
            const short* cb = cur + col*PS + g*8;
            #pragma unroll
            for (int t=0;t<8;t++) {
                bf16x8 wf = *(const bf16x8*)(cb + t*16*PS);
                acc[0][t] = __builtin_amdgcn_mfma_f32_16x16x32_bf16(af0, wf, acc[0][t], 0,0,0);
                acc[1][t] = __builtin_amdgcn_mfma_f32_16x16x32_bf16(af1, wf, acc[1][t], 0,0,0);
            }
        }
        // ks = 1  (kstep j = 2ch+1)
        {
            bf16x8 af0 = cvt8(s1a,s1b);
            bf16x8 af1 = cvt8(s1c,s1d);
            if (more) LOADA(2*ch+3, s1a,s1b,s1c,s1d);
            const short* cb = cur + col*PS + 32 + g*8;
            #pragma unroll
            for (int t=0;t<8;t++) {
                bf16x8 wf = *(const bf16x8*)(cb + t*16*PS);
                acc[0][t] = __builtin_amdgcn_mfma_f32_16x16x32_bf16(af0, wf, acc[0][t], 0,0,0);
                acc[1][t] = __builtin_amdgcn_mfma_f32_16x16x32_bf16(af1, wf, acc[1][t], 0,0,0);
            }
        }
        if (more) {
            *(bf16x8*)(nxtd + 0*32*PS) = w0;
            *(bf16x8*)(nxtd + 1*32*PS) = w1;
            *(bf16x8*)(nxtd + 2*32*PS) = w2;
            *(bf16x8*)(nxtd + 3*32*PS) = w3;
        }
        __syncthreads();
    }
}

__global__ __launch_bounds__(BLOCK) void fused(
    const float* __restrict__ lm,  const float* __restrict__ gnn,
    const float* __restrict__ ngn,
    const float* __restrict__ lm_b, const float* __restrict__ gnn_b,
    const short* __restrict__ W1B,  const short* __restrict__ W2B,
    float* __restrict__ partials)
{
    __shared__ short W_lds[2*LBUF];
    __shared__ float sp[4], sn[4];

    const int tid  = threadIdx.x;
    const int lane = tid & 63;
    const int win  = tid >> 6;
    const int col  = lane & 15;
    const int g    = lane >> 4;
    const long r0  = (long)blockIdx.x * MTILE + win*32;   // this wave's first row

    const float CC   = 1.0f / 11008.0f;
    const float LOGC = -9.3063777f;      // log(1/11008)

    f32x4 accL[2][8], accG[2][8];
    float pos_acc = 0.f, neg_acc = 0.f;

    // ---- lm GEMM ----
    gemm_phase<LMD/64, LMD, false>((const char*)(lm + r0*LMD), (long)LMD*4, W1B,
                                   nullptr, W_lds, tid, col, g, accL);
    #pragma unroll
    for (int t=0;t<8;t++) {
        float b = lm_b[t*16+col];
        #pragma unroll
        for (int m=0;m<2;m++)
            #pragma unroll
            for (int r=0;r<4;r++) accL[m][t][r] += b;
    }

    const char* clampG = (const char*)gnn + (size_t)NROWS*GNND*4 - 16;
    const char* clampN = (const char*)ngn + (size_t)NROWS*GNND*4 - 16;

    // ---- pos branch ----
    gemm_phase<K2/64, K2, true>((const char*)gnn + r0*(long)GNND*4, (long)GNND*4, W2B,
                                clampG, W_lds, tid, col, g, accG);
    #pragma unroll
    for (int t=0;t<8;t++) {
        float b = gnn_b[t*16+col];
        #pragma unroll
        for (int m=0;m<2;m++)
            #pragma unroll
            for (int r=0;r<4;r++) accG[m][t][r] += b;
    }
    #pragma unroll
    for (int m=0;m<2;m++)
        #pragma unroll
        for (int r=0;r<4;r++) {
            float lg=0.f, ll=0.f, gg=0.f;
            #pragma unroll
            for (int t=0;t<8;t++) {
                float lv=accL[m][t][r], gv=accG[m][t][r];
                lg += lv*gv; ll += lv*lv; gg += gv*gv;
            }
            lg=red16(lg); ll=red16(ll); gg=red16(gg);
            float d  = lg * rsqrtf(ll*gg);
            float pi = d - logf(expf(d)+CC);     // log(ratio)
            if (col==0) pos_acc += pi;
        }

    // ---- neg branch ----
    gemm_phase<K2/64, K2, true>((const char*)ngn + r0*(long)GNND*4, (long)GNND*4, W2B,
                                clampN, W_lds, tid, col, g, accG);
    #pragma unroll
    for (int t=0;t<8;t++) {
        float b = gnn_b[t*16+col];
        #pragma unroll
        for (int m=0;m<2;m++)
            #pragma unroll
            for (int r=0;r<4;r++) accG[m][t][r] += b;
    }
    #pragma unroll
    for (int m=0;m<2;m++)
        #pragma unroll
        for (int r=0;r<4;r++) {
            float ln=0.f, nn=0.f, ll=0.f;
            #pragma unroll
            for (int t=0;t<8;t++) {
                float lv=accL[m][t][r], nv=accG[m][t][r];
                ln += lv*nv; nn += nv*nv; ll += lv*lv;
            }
            ln=red16(ln); nn=red16(nn); ll=red16(ll);
            float d  = ln * rsqrtf(ll*nn);
            float ni = LOGC - logf(expf(d)+CC);  // log(1-ratio)
            if (col==0) neg_acc += ni;
        }

    // ---- wave + block reduce ----
    #pragma unroll
    for (int m=1;m<64;m<<=1) {
        pos_acc += __shfl_xor(pos_acc, m, 64);
        neg_acc += __shfl_xor(neg_acc, m, 64);
    }
    if (lane==0) { sp[win]=pos_acc; sn[win]=neg_acc; }
    __syncthreads();
    if (tid==0) {
        float p=0.f,n=0.f;
        #pragma unroll
        for (int w=0;w<4;w++){ p+=sp[w]; n+=sn[w]; }
        partials[blockIdx.x*2]   = p;
        partials[blockIdx.x*2+1] = n;
    }
}

__global__ void finalize(const float* __restrict__ partials, float* __restrict__ out)
{
    __shared__ float sp[BLOCK], sn[BLOCK];
    float p=0.f, n=0.f;
    for (int i=threadIdx.x; i<NBLK; i+=BLOCK) { p += partials[2*i]; n += partials[2*i+1]; }
    sp[threadIdx.x]=p; sn[threadIdx.x]=n;
    __syncthreads();
    for (int s=BLOCK/2; s>0; s>>=1) {
        if (threadIdx.x < s) { sp[threadIdx.x]+=sp[threadIdx.x+s]; sn[threadIdx.x]+=sn[threadIdx.x+s]; }
        __syncthreads();
    }
    if (threadIdx.x==0) out[0] = -(sp[0]+sn[0]) / (float)NROWS;
}

extern "C" void kernel_launch(void* const* d_in, const int* in_sizes, int n_in,
                              void* d_out, int out_size, void* d_ws, size_t ws_size,
                              hipStream_t stream)
{
    const float* lm    = (const float*)d_in[0];
    const float* gnn   = (const float*)d_in[1];
    const float* ngn   = (const float*)d_in[2];
    const float* lm_W  = (const float*)d_in[3];
    const float* lm_b  = (const float*)d_in[4];
    const float* gnn_W = (const float*)d_in[5];
    const float* gnn_b = (const float*)d_in[6];

    short* W1B = (short*)d_ws;                                   // 128*1024*2 = 262144 B
    short* W2B = (short*)((char*)d_ws + 262144);                 // 128*256*2  =  65536 B
    float* partials = (float*)((char*)d_ws + 262144 + 65536);    // 8 KB

    prep_weights<<<512, BLOCK, 0, stream>>>(lm_W, gnn_W, W1B, W2B);
    fused<<<NBLK, BLOCK, 0, stream>>>(lm, gnn, ngn, lm_b, gnn_b, W1B, W2B, partials);
    finalize<<<1, BLOCK, 0, stream>>>(partials, (float*)d_out);
}

// Round 4
// 202.134 us; speedup vs baseline: 2.2299x; 1.0435x over previous
//
#include <hip/hip_runtime.h>
#include <hip/hip_bf16.h>
#include <stdint.h>

#define NROWS   131072
#define LMD     1024
#define GNND    200
#define K2      256              // gnn K padded (W zero-padded)
#define HD      128
#define BLOCK   256
#define MTILE   64               // rows per block (16 per wave)
#define NBLK    (NROWS/MTILE)    // 2048
#define CHSH    8192             // shorts per W chunk: 128 rows x 64 k

typedef __attribute__((ext_vector_type(4))) float  f32x4;
typedef __attribute__((ext_vector_type(8))) short  bf16x8;

__device__ __forceinline__ short f2bf(float x) {
    union { __hip_bfloat16 h; short s; } u;
    u.h = __float2bfloat16(x);
    return u.s;
}

__device__ __forceinline__ bf16x8 cvt8(f32x4 a, f32x4 b) {
    bf16x8 r;
    r[0]=f2bf(a[0]); r[1]=f2bf(a[1]); r[2]=f2bf(a[2]); r[3]=f2bf(a[3]);
    r[4]=f2bf(b[0]); r[5]=f2bf(b[1]); r[6]=f2bf(b[2]); r[7]=f2bf(b[3]);
    return r;
}

__device__ __forceinline__ float red16(float v) {
    #pragma unroll
    for (int m=1; m<16; m<<=1) v += __shfl_xor(v, m, 16);
    return v;
}

// ---- prep: chunk-major, swizzle-baked W panels (bf16) ----
// W1S[ch][row][e] = bf16( lm_W[kk][row] ),  kk = ch*64 + (e ^ ((row&7)*8))
// W2S likewise over gnn_W, zero for kk >= 200.
__global__ void prep_weights(const float* __restrict__ lm_W,
                             const float* __restrict__ gnn_W,
                             short* __restrict__ W1S, short* __restrict__ W2S)
{
    int idx = blockIdx.x*BLOCK + threadIdx.x;     // 512*256 = 131072 = 16 chunks * 8192
    int row = (idx >> 6) & 127;
    int e   = idx & 63;
    int kk  = (idx >> 13)*64 + (e ^ ((row & 7)*8));
    W1S[idx] = f2bf(lm_W[(long)kk*HD + row]);
    if (idx < 4*CHSH) {
        W2S[idx] = (kk < GNND) ? f2bf(gnn_W[(long)kk*HD + row]) : (short)0;
    }
}

// One GEMM phase over K = NCH*64 for this wave's 16 rows x 128 cols.
// W: chunk-major global -> LDS via global_load_lds, double-buffered, counted-vmcnt barriers.
// A: global->reg, depth-2 kstep prefetch, loads stay in flight across barriers.
template<int NCH, bool CLAMP>
__device__ __forceinline__ void gemm_phase(const char* Abase, long rowB,
                                           const char* __restrict__ Wsrc,
                                           const char* clampP, short* lds,
                                           int tid, int win, int col, int g,
                                           f32x4 (&acc)[8])
{
    const f32x4 fz = {0.f,0.f,0.f,0.f};
    #pragma unroll
    for (int t=0;t<8;t++) acc[t] = fz;

    const int lane16 = (tid & 63) * 16;
    const char* a = Abase + (long)col*rowB + g*32;

    auto ISSUEW = [&](int ch, short* buf) {
        #pragma unroll
        for (int i=0;i<4;i++) {
            __builtin_amdgcn_global_load_lds(
                (const __attribute__((address_space(1))) unsigned int*)
                    (Wsrc + (long)ch*16384 + win*4096 + i*1024 + lane16),
                (__attribute__((address_space(3))) unsigned int*)
                    ((char*)buf + win*4096 + i*1024 + lane16),
                16, 0, 0);
        }
        __builtin_amdgcn_sched_barrier(0);   // keep W-lds loads oldest in vmcnt order
    };

    auto LOADA = [&](int J, f32x4& sa, f32x4& sb) {
        const char* p0 = a + (long)J*128;
        const char* p1 = p0 + 16;
        if constexpr (CLAMP) {
            if (p0 > clampP) p0 = clampP;
            if (p1 > clampP) p1 = clampP;
        }
        sa = *(const f32x4*)p0; sb = *(const f32x4*)p1;
    };

    const int eb0 = (g*8) ^ ((col&7)*8);          // kstep ks: e' = (ks*32+g*8) ^ sw
    const int eb1 = (32 + g*8) ^ ((col&7)*8);

    f32x4 s0a,s0b,s1a,s1b;

    ISSUEW(0, lds);
    LOADA(0, s0a,s0b);
    LOADA(1, s1a,s1b);
    asm volatile("s_waitcnt vmcnt(4)" ::: "memory");
    __builtin_amdgcn_sched_barrier(0);
    __builtin_amdgcn_s_barrier();

    for (int ch = 0; ch < NCH; ++ch) {
        short* cur = lds + (ch&1)*CHSH;
        short* nxt = lds + ((ch+1)&1)*CHSH;
        const bool more = (ch+1 < NCH);
        if (more) ISSUEW(ch+1, nxt);
        // kstep 0
        {
            f32x4 va=s0a, vb=s0b;
            if (more) LOADA(2*ch+2, s0a,s0b);
            bf16x8 af = cvt8(va, vb);
            const short* cb = cur + col*64 + eb0;
            #pragma unroll
            for (int t=0;t<8;t++) {
                bf16x8 wf = *(const bf16x8*)(cb + t*1024);
                acc[t] = __builtin_amdgcn_mfma_f32_16x16x32_bf16(af, wf, acc[t], 0,0,0);
            }
        }
        // kstep 1
        {
            f32x4 va=s1a, vb=s1b;
            if (more) LOADA(2*ch+3, s1a,s1b);
            bf16x8 af = cvt8(va, vb);
            const short* cb = cur + col*64 + eb1;
            #pragma unroll
            for (int t=0;t<8;t++) {
                bf16x8 wf = *(const bf16x8*)(cb + t*1024);
                acc[t] = __builtin_amdgcn_mfma_f32_16x16x32_bf16(af, wf, acc[t], 0,0,0);
            }
        }
        if (more) {
            asm volatile("s_waitcnt vmcnt(4)" ::: "memory");   // W(ch+1) landed; A stays in flight
            __builtin_amdgcn_sched_barrier(0);
        }
        __builtin_amdgcn_s_barrier();
    }
}

__global__ __launch_bounds__(BLOCK) void fused(
    const float* __restrict__ lm,  const float* __restrict__ gnn,
    const float* __restrict__ ngn,
    const float* __restrict__ lm_b, const float* __restrict__ gnn_b,
    const char* __restrict__ W1S,  const char* __restrict__ W2S,
    float* __restrict__ partials)
{
    __shared__ short W_lds[2*CHSH];
    __shared__ float sp[4], sn[4];

    const int tid  = threadIdx.x;
    const int lane = tid & 63;
    const int win  = tid >> 6;
    const int col  = lane & 15;
    const int g    = lane >> 4;
    const long r0  = (long)blockIdx.x * MTILE + win*16;   // this wave's first row

    const float CC   = 1.0f / 11008.0f;
    const float LOGC = -9.3063777f;      // log(1/11008)

    f32x4 accL[8], accG[8];
    float pos_acc = 0.f, neg_acc = 0.f;

    // ---- lm GEMM ----
    gemm_phase<LMD/64, false>((const char*)(lm + r0*LMD), (long)LMD*4, W1S,
                              nullptr, W_lds, tid, win, col, g, accL);
    #pragma unroll
    for (int t=0;t<8;t++) {
        float b = lm_b[t*16+col];
        #pragma unroll
        for (int r=0;r<4;r++) accL[t][r] += b;
    }

    const char* clampG = (const char*)gnn + (size_t)NROWS*GNND*4 - 16;
    const char* clampN = (const char*)ngn + (size_t)NROWS*GNND*4 - 16;

    // ---- pos branch ----
    gemm_phase<K2/64, true>((const char*)gnn + r0*(long)GNND*4, (long)GNND*4, W2S,
                            clampG, W_lds, tid, win, col, g, accG);
    #pragma unroll
    for (int t=0;t<8;t++) {
        float b = gnn_b[t*16+col];
        #pragma unroll
        for (int r=0;r<4;r++) accG[t][r] += b;
    }
    #pragma unroll
    for (int r=0;r<4;r++) {
        float lg=0.f, ll=0.f, gg=0.f;
        #pragma unroll
        for (int t=0;t<8;t++) {
            float lv=accL[t][r], gv=accG[t][r];
            lg += lv*gv; ll += lv*lv; gg += gv*gv;
        }
        lg=red16(lg); ll=red16(ll); gg=red16(gg);
        float d  = lg * rsqrtf(ll*gg);
        float pi = d - logf(expf(d)+CC);     // log(ratio)
        if (col==0) pos_acc += pi;
    }

    // ---- neg branch ----
    gemm_phase<K2/64, true>((const char*)ngn + r0*(long)GNND*4, (long)GNND*4, W2S,
                            clampN, W_lds, tid, win, col, g, accG);
    #pragma unroll
    for (int t=0;t<8;t++) {
        float b = gnn_b[t*16+col];
        #pragma unroll
        for (int r=0;r<4;r++) accG[t][r] += b;
    }
    #pragma unroll
    for (int r=0;r<4;r++) {
        float ln=0.f, nn=0.f, ll=0.f;
        #pragma unroll
        for (int t=0;t<8;t++) {
            float lv=accL[t][r], nv=accG[t][r];
            ln += lv*nv; nn += nv*nv; ll += lv*lv;
        }
        ln=red16(ln); nn=red16(nn); ll=red16(ll);
        float d  = ln * rsqrtf(ll*nn);
        float ni = LOGC - logf(expf(d)+CC);  // log(1-ratio)
        if (col==0) neg_acc += ni;
    }

    // ---- wave + block reduce ----
    #pragma unroll
    for (int m=1;m<64;m<<=1) {
        pos_acc += __shfl_xor(pos_acc, m, 64);
        neg_acc += __shfl_xor(neg_acc, m, 64);
    }
    if (lane==0) { sp[win]=pos_acc; sn[win]=neg_acc; }
    __syncthreads();
    if (tid==0) {
        float p=0.f,n=0.f;
        #pragma unroll
        for (int w=0;w<4;w++){ p+=sp[w]; n+=sn[w]; }
        partials[blockIdx.x*2]   = p;
        partials[blockIdx.x*2+1] = n;
    }
}

__global__ void finalize(const float* __restrict__ partials, float* __restrict__ out)
{
    __shared__ float sp[BLOCK], sn[BLOCK];
    float p=0.f, n=0.f;
    for (int i=threadIdx.x; i<NBLK; i+=BLOCK) { p += partials[2*i]; n += partials[2*i+1]; }
    sp[threadIdx.x]=p; sn[threadIdx.x]=n;
    __syncthreads();
    for (int s=BLOCK/2; s>0; s>>=1) {
        if (threadIdx.x < s) { sp[threadIdx.x]+=sp[threadIdx.x+s]; sn[threadIdx.x]+=sn[threadIdx.x+s]; }
        __syncthreads();
    }
    if (threadIdx.x==0) out[0] = -(sp[0]+sn[0]) / (float)NROWS;
}

extern "C" void kernel_launch(void* const* d_in, const int* in_sizes, int n_in,
                              void* d_out, int out_size, void* d_ws, size_t ws_size,
                              hipStream_t stream)
{
    const float* lm    = (const float*)d_in[0];
    const float* gnn   = (const float*)d_in[1];
    const float* ngn   = (const float*)d_in[2];
    const float* lm_W  = (const float*)d_in[3];
    const float* lm_b  = (const float*)d_in[4];
    const float* gnn_W = (const float*)d_in[5];
    const float* gnn_b = (const float*)d_in[6];

    short* W1S = (short*)d_ws;                                   // 16*8192*2 = 262144 B
    short* W2S = (short*)((char*)d_ws + 262144);                 // 4*8192*2  =  65536 B
    float* partials = (float*)((char*)d_ws + 262144 + 65536);    // 16 KB

    prep_weights<<<512, BLOCK, 0, stream>>>(lm_W, gnn_W, W1S, W2S);
    fused<<<NBLK, BLOCK, 0, stream>>>(lm, gnn, ngn, lm_b, gnn_b,
                                      (const char*)W1S, (const char*)W2S, partials);
    finalize<<<1, BLOCK, 0, stream>>>(partials, (float*)d_out);
}

// Round 5
// 182.103 us; speedup vs baseline: 2.4752x; 1.1100x over previous
//
#include <hip/hip_runtime.h>
#include <hip/hip_bf16.h>
#include <stdint.h>

#define NROWS   131072
#define LMD     1024
#define GNND    200
#define K2      256
#define HD      128
#define BLOCK   256
#define MTILE   64               // rows per block (16 per wave)
#define NBLK    (NROWS/MTILE)    // 2048
#define CHB     16384            // W chunk bytes (128 rows x 64 k bf16)

typedef __attribute__((ext_vector_type(4))) float  f32x4;
typedef __attribute__((ext_vector_type(8))) short  bf16x8;

__device__ __forceinline__ short f2bf(float x) {
    union { __hip_bfloat16 h; short s; } u;
    u.h = __float2bfloat16(x);
    return u.s;
}

__device__ __forceinline__ bf16x8 cvt8(f32x4 a, f32x4 b) {
    bf16x8 r;
    r[0]=f2bf(a[0]); r[1]=f2bf(a[1]); r[2]=f2bf(a[2]); r[3]=f2bf(a[3]);
    r[4]=f2bf(b[0]); r[5]=f2bf(b[1]); r[6]=f2bf(b[2]); r[7]=f2bf(b[3]);
    return r;
}

__device__ __forceinline__ float red16(float v) {
    #pragma unroll
    for (int m=1; m<16; m<<=1) v += __shfl_xor(v, m, 16);
    return v;
}

// ---- prep: chunk-major, swizzle-baked W panels (bf16) ----
// W1S[ch][row][e] = bf16( lm_W[kk][row] ),  kk = ch*64 + (e ^ ((row&7)*8))
__global__ void prep_weights(const float* __restrict__ lm_W,
                             const float* __restrict__ gnn_W,
                             short* __restrict__ W1S, short* __restrict__ W2S)
{
    int idx = blockIdx.x*BLOCK + threadIdx.x;     // 512*256 = 131072 = 16 chunks * 8192
    int row = (idx >> 6) & 127;
    int e   = idx & 63;
    int kk  = (idx >> 13)*64 + (e ^ ((row & 7)*8));
    W1S[idx] = f2bf(lm_W[(long)kk*HD + row]);
    if (idx < 4*8192) {
        W2S[idx] = (kk < GNND) ? f2bf(gnn_W[(long)kk*HD + row]) : (short)0;
    }
}

__device__ __forceinline__ void issueW(const char* src, char* dst, int off) {
    #pragma unroll
    for (int i=0;i<4;i++) {
        __builtin_amdgcn_global_load_lds(
            (const __attribute__((address_space(1))) unsigned int*)(src + i*1024 + off),
            (__attribute__((address_space(3))) unsigned int*)(dst + i*1024 + off),
            16, 0, 0);
    }
}

template<bool CLAMP>
__device__ __forceinline__ void loadA(const char* base, int byteoff, const char* clampP,
                                      f32x4& sa, f32x4& sb) {
    const char* p0 = base + byteoff;
    const char* p1 = p0 + 16;
    if constexpr (CLAMP) {
        if (p0 > clampP) p0 = clampP;
        if (p1 > clampP) p1 = clampP;
    }
    sa = *(const f32x4*)p0;
    sb = *(const f32x4*)p1;
}

__device__ __forceinline__ void chunkMFMA(const short* cur, int col, int g,
                                          f32x4 (&acc)[8],
                                          f32x4 p0a, f32x4 p0b, f32x4 p1a, f32x4 p1b)
{
    const int sw  = (col & 7) * 8;
    const int eb0 = (g*8) ^ sw;
    const int eb1 = (32 + g*8) ^ sw;
    {
        bf16x8 af = cvt8(p0a, p0b);
        const short* cb = cur + col*64 + eb0;
        #pragma unroll
        for (int t=0;t<8;t++) {
            bf16x8 wf = *(const bf16x8*)(cb + t*1024);
            acc[t] = __builtin_amdgcn_mfma_f32_16x16x32_bf16(af, wf, acc[t], 0,0,0);
        }
    }
    {
        bf16x8 af = cvt8(p1a, p1b);
        const short* cb = cur + col*64 + eb1;
        #pragma unroll
        for (int t=0;t<8;t++) {
            bf16x8 wf = *(const bf16x8*)(cb + t*1024);
            acc[t] = __builtin_amdgcn_mfma_f32_16x16x32_bf16(af, wf, acc[t], 0,0,0);
        }
    }
}

// One pipeline chunk. MW: 1=issue W(c+2). MA: 0 none, 1 plain A, 2 clamped A. VMC: >=0 -> s_waitcnt vmcnt(VMC)+s_barrier.
template<int MW, int MA, int VMC>
__device__ __forceinline__ void step(const short* cur, int col, int g, f32x4 (&acc)[8],
                                     f32x4& s0a, f32x4& s0b, f32x4& s1a, f32x4& s1b,
                                     const char* wsrc, char* wdst, int woff,
                                     const char* abase, int aoff, const char* aclamp)
{
    f32x4 u0a=s0a, u0b=s0b, u1a=s1a, u1b=s1b;   // consume copies (SSA-renamed)
    if constexpr (MW == 1) issueW(wsrc, wdst, woff);
    if constexpr (MA == 1) {
        loadA<false>(abase, aoff,     aclamp, s0a, s0b);
        loadA<false>(abase, aoff+128, aclamp, s1a, s1b);
    }
    if constexpr (MA == 2) {
        loadA<true>(abase, aoff,     aclamp, s0a, s0b);
        loadA<true>(abase, aoff+128, aclamp, s1a, s1b);
    }
    __builtin_amdgcn_sched_barrier(0);
    chunkMFMA(cur, col, g, acc, u0a, u0b, u1a, u1b);
    if constexpr (VMC >= 0) {
        __builtin_amdgcn_sched_barrier(0);
        asm volatile("s_waitcnt vmcnt(%0)" :: "n"(VMC) : "memory");
        __builtin_amdgcn_sched_barrier(0);
        __builtin_amdgcn_s_barrier();
        __builtin_amdgcn_sched_barrier(0);
    }
}

__global__ __launch_bounds__(BLOCK) void fused(
    const float* __restrict__ lm,  const float* __restrict__ gnn,
    const float* __restrict__ ngn,
    const float* __restrict__ lm_b, const float* __restrict__ gnn_b,
    const char* __restrict__ W1S,  const char* __restrict__ W2S,
    float* __restrict__ partials)
{
    __shared__ char lbuf[4*CHB];
    __shared__ float sp[4], sn[4];

    const int tid  = threadIdx.x;
    const int lane = tid & 63;
    const int win  = tid >> 6;
    const int col  = lane & 15;
    const int g    = lane >> 4;
    const int woff = win*4096 + lane*16;
    const long row = (long)blockIdx.x * MTILE + win*16 + col;

    const char* aL = (const char*)lm  + row*(LMD*4L)  + g*32;
    const char* aG = (const char*)gnn + row*(GNND*4L) + g*32;
    const char* aN = (const char*)ngn + row*(GNND*4L) + g*32;
    const char* clampG = (const char*)gnn + (size_t)NROWS*GNND*4 - 16;
    const char* clampN = (const char*)ngn + (size_t)NROWS*GNND*4 - 16;

    const float CC   = 1.0f / 11008.0f;
    const float LOGC = -9.3063777f;      // log(1/11008)
    const f32x4 fz = {0.f,0.f,0.f,0.f};

    short* const b0 = (short*)(lbuf);
    short* const b1 = (short*)(lbuf + CHB);
    short* const b2 = (short*)(lbuf + 2*CHB);
    short* const b3 = (short*)(lbuf + 3*CHB);

    f32x4 accL[8], accG[8];
    #pragma unroll
    for (int t=0;t<8;t++) accL[t] = fz;

    f32x4 E0a,E0b,E1a,E1b;   // slots for even chunks
    f32x4 O0a,O0b,O1a,O1b;   // slots for odd chunks

    float pos_acc = 0.f, neg_acc = 0.f;

    // ---- prologue: W1(0)->b0, W1(1)->b1, A(0)->E, A(1)->O ----
    issueW(W1S + 0*CHB, lbuf + 0*CHB, woff);
    issueW(W1S + 1*CHB, lbuf + 1*CHB, woff);
    loadA<false>(aL,   0, nullptr, E0a,E0b);
    loadA<false>(aL, 128, nullptr, E1a,E1b);
    loadA<false>(aL, 256, nullptr, O0a,O0b);
    loadA<false>(aL, 384, nullptr, O1a,O1b);
    __builtin_amdgcn_sched_barrier(0);
    asm volatile("s_waitcnt vmcnt(12)" ::: "memory");   // W1(0) landed; rest in flight
    __builtin_amdgcn_sched_barrier(0);
    __builtin_amdgcn_s_barrier();
    __builtin_amdgcn_sched_barrier(0);

    // ---- lm chunks 0..11 (generic, W(c+2), A(c+2)) ----
    for (int c = 0; c < 12; c += 2) {
        short* curE = (short*)(lbuf + (size_t)( c    & 3)*CHB);
        char*  wdE  =          lbuf + (size_t)((c+2) & 3)*CHB;
        step<1,1,12>(curE, col, g, accL, E0a,E0b,E1a,E1b,
                     W1S + (size_t)(c+2)*CHB, wdE, woff, aL, (c+2)*256, nullptr);
        short* curO = (short*)(lbuf + (size_t)((c+1) & 3)*CHB);
        char*  wdO  =          lbuf + (size_t)((c+3) & 3)*CHB;
        step<1,1,12>(curO, col, g, accL, O0a,O0b,O1a,O1b,
                     W1S + (size_t)(c+3)*CHB, wdO, woff, aL, (c+3)*256, nullptr);
    }
    // ---- lm chunks 12..15 (tail: cross-phase issues) ----
    step<1,1,12>(b0, col, g, accL, E0a,E0b,E1a,E1b, W1S + 14*CHB, (char*)b2, woff, aL, 14*256, nullptr); // c=12
    step<1,1,12>(b1, col, g, accL, O0a,O0b,O1a,O1b, W1S + 15*CHB, (char*)b3, woff, aL, 15*256, nullptr); // c=13
    step<1,2,12>(b2, col, g, accL, E0a,E0b,E1a,E1b, W2S +  0*CHB, (char*)b0, woff, aG,      0, clampG);  // c=14
    step<1,2,12>(b3, col, g, accL, O0a,O0b,O1a,O1b, W2S +  1*CHB, (char*)b1, woff, aG,    256, clampG);  // c=15

    // lm bias
    #pragma unroll
    for (int t=0;t<8;t++) {
        float b = lm_b[t*16+col];
        #pragma unroll
        for (int r=0;r<4;r++) accL[t][r] += b;
    }
    #pragma unroll
    for (int t=0;t<8;t++) accG[t] = fz;

    // ---- pos chunks 16..19 ----
    step<1,2,12>(b0, col, g, accG, E0a,E0b,E1a,E1b, W2S + 2*CHB, (char*)b2, woff, aG, 512, clampG);      // c=16
    step<1,2,12>(b1, col, g, accG, O0a,O0b,O1a,O1b, W2S + 3*CHB, (char*)b3, woff, aG, 768, clampG);      // c=17
    step<0,2, 8>(b2, col, g, accG, E0a,E0b,E1a,E1b, nullptr, nullptr, 0,    aN,   0, clampN);            // c=18
    step<0,2,-1>(b3, col, g, accG, O0a,O0b,O1a,O1b, nullptr, nullptr, 0,    aN, 256, clampN);            // c=19

    // pos epilogue (ngn A loads for chunks 20/21 in flight underneath)
    #pragma unroll
    for (int t=0;t<8;t++) {
        float b = gnn_b[t*16+col];
        #pragma unroll
        for (int r=0;r<4;r++) accG[t][r] += b;
    }
    #pragma unroll
    for (int r=0;r<4;r++) {
        float lg=0.f, ll=0.f, gg=0.f;
        #pragma unroll
        for (int t=0;t<8;t++) {
            float lv=accL[t][r], gv=accG[t][r];
            lg += lv*gv; ll += lv*lv; gg += gv*gv;
        }
        lg=red16(lg); ll=red16(ll); gg=red16(gg);
        float d  = lg * rsqrtf(ll*gg);
        float pi = d - logf(expf(d)+CC);     // log(ratio)
        if (col==0) pos_acc += pi;
    }
    #pragma unroll
    for (int t=0;t<8;t++) accG[t] = fz;

    // ---- neg chunks 20..23 (barrier-free: W2 resident in b0..b3) ----
    step<0,2,-1>(b0, col, g, accG, E0a,E0b,E1a,E1b, nullptr, nullptr, 0, aN, 512, clampN);               // c=20
    step<0,2,-1>(b1, col, g, accG, O0a,O0b,O1a,O1b, nullptr, nullptr, 0, aN, 768, clampN);               // c=21
    step<0,0,-1>(b2, col, g, accG, E0a,E0b,E1a,E1b, nullptr, nullptr, 0, nullptr, 0, nullptr);           // c=22
    step<0,0,-1>(b3, col, g, accG, O0a,O0b,O1a,O1b, nullptr, nullptr, 0, nullptr, 0, nullptr);           // c=23

    // neg epilogue
    #pragma unroll
    for (int t=0;t<8;t++) {
        float b = gnn_b[t*16+col];
        #pragma unroll
        for (int r=0;r<4;r++) accG[t][r] += b;
    }
    #pragma unroll
    for (int r=0;r<4;r++) {
        float ln=0.f, nn=0.f, ll=0.f;
        #pragma unroll
        for (int t=0;t<8;t++) {
            float lv=accL[t][r], nv=accG[t][r];
            ln += lv*nv; nn += nv*nv; ll += lv*lv;
        }
        ln=red16(ln); nn=red16(nn); ll=red16(ll);
        float d  = ln * rsqrtf(ll*nn);
        float ni = LOGC - logf(expf(d)+CC);  // log(1-ratio)
        if (col==0) neg_acc += ni;
    }

    // ---- wave + block reduce ----
    #pragma unroll
    for (int m=1;m<64;m<<=1) {
        pos_acc += __shfl_xor(pos_acc, m, 64);
        neg_acc += __shfl_xor(neg_acc, m, 64);
    }
    if (lane==0) { sp[win]=pos_acc; sn[win]=neg_acc; }
    __syncthreads();
    if (tid==0) {
        float p=0.f,n=0.f;
        #pragma unroll
        for (int w=0;w<4;w++){ p+=sp[w]; n+=sn[w]; }
        partials[blockIdx.x*2]   = p;
        partials[blockIdx.x*2+1] = n;
    }
}

__global__ void finalize(const float* __restrict__ partials, float* __restrict__ out)
{
    __shared__ float sp[BLOCK], sn[BLOCK];
    float p=0.f, n=0.f;
    for (int i=threadIdx.x; i<NBLK; i+=BLOCK) { p += partials[2*i]; n += partials[2*i+1]; }
    sp[threadIdx.x]=p; sn[threadIdx.x]=n;
    __syncthreads();
    for (int s=BLOCK/2; s>0; s>>=1) {
        if (threadIdx.x < s) { sp[threadIdx.x]+=sp[threadIdx.x+s]; sn[threadIdx.x]+=sn[threadIdx.x+s]; }
        __syncthreads();
    }
    if (threadIdx.x==0) out[0] = -(sp[0]+sn[0]) / (float)NROWS;
}

extern "C" void kernel_launch(void* const* d_in, const int* in_sizes, int n_in,
                              void* d_out, int out_size, void* d_ws, size_t ws_size,
                              hipStream_t stream)
{
    const float* lm    = (const float*)d_in[0];
    const float* gnn   = (const float*)d_in[1];
    const float* ngn   = (const float*)d_in[2];
    const float* lm_W  = (const float*)d_in[3];
    const float* lm_b  = (const float*)d_in[4];
    const float* gnn_W = (const float*)d_in[5];
    const float* gnn_b = (const float*)d_in[6];

    short* W1S = (short*)d_ws;                                   // 16*16384 = 262144 B
    short* W2S = (short*)((char*)d_ws + 262144);                 // 4*16384  =  65536 B
    float* partials = (float*)((char*)d_ws + 262144 + 65536);    // 16 KB

    prep_weights<<<512, BLOCK, 0, stream>>>(lm_W, gnn_W, W1S, W2S);
    fused<<<NBLK, BLOCK, 0, stream>>>(lm, gnn, ngn, lm_b, gnn_b,
                                      (const char*)W1S, (const char*)W2S, partials);
    finalize<<<1, BLOCK, 0, stream>>>(partials, (float*)d_out);
}